// Round 5
// baseline (1432.696 us; speedup 1.0000x reference)
//
#include <hip/hip_runtime.h>
#include <math.h>

// Problem constants (N=80000, Rr=5, A=8, D=32, T=32, K=8 rotations, ROT_DELTA=1)
#define RR 5
#define AA 8
#define DD 32
#define TT 32
#define KK 8

#define RT2 0.70710678118654752f

typedef float v2f __attribute__((ext_vector_type(2)));
typedef float v4f __attribute__((ext_vector_type(4)));

static __device__ __forceinline__ v2f pkfma(v2f a, v2f b, v2f c) {
#if __has_builtin(__builtin_elementwise_fma)
    return __builtin_elementwise_fma(a, b, c);
#else
    v2f r; r.x = fmaf(a.x, b.x, c.x); r.y = fmaf(a.y, b.y, c.y); return r;
#endif
}

// ---------------------------------------------------------------------------
// W spectral precompute: for t=tOct*8+tIn, spectra packed for wave-uniform
// scalar loads in the GEMM:
//   Ws[(((r*4 + tOct)*32 + d)*64) + tIn*8 + f] , f-pack = [F0,F4,R1,I1,R2,I2,R3,I3]
// One thread per (t,r,d) = 5120.
// ---------------------------------------------------------------------------
__global__ void wdft_kernel(const float* __restrict__ W, float* __restrict__ Ws) {
    int idx = blockIdx.x * 256 + threadIdx.x;
    if (idx >= TT * RR * DD) return;
    int d = idx & 31;
    int tr = idx >> 5;      // t*5+r
    int t = tr / 5;
    int r = tr - t * 5;
    float xa[8];
    #pragma unroll
    for (int a = 0; a < 8; ++a) xa[a] = W[(tr * 8 + a) * 32 + d];
    float s0 = xa[0] + xa[4], d0 = xa[0] - xa[4];
    float s1 = xa[1] + xa[5], d1 = xa[1] - xa[5];
    float s2 = xa[2] + xa[6], d2 = xa[2] - xa[6];
    float s3 = xa[3] + xa[7], d3 = xa[3] - xa[7];
    float s02 = s0 + s2, s13 = s1 + s3;
    float F0 = s02 + s13, F4 = s02 - s13;
    float R2 = s0 - s2, I2 = s3 - s1;
    float u = RT2 * (d1 - d3), v = RT2 * (d1 + d3);
    float R1 = d0 + u, R3 = d0 - u;
    float I1 = -d2 - v, I3 = d2 - v;
    float* o = &Ws[(size_t)(((r * 4 + (t >> 3)) * 32 + d) * 64) + (t & 7) * 8];
    o[0] = F0; o[1] = F4; o[2] = R1; o[3] = I1;
    o[4] = R2; o[5] = I2; o[6] = R3; o[7] = I3;
}

// ---------------------------------------------------------------------------
// Fused kernel: gather + barycentric interp + forward DFT8 + spectral GEMM
// (vs conj(W-spectrum), W through the SCALAR pipe) + IDFT8 + bias + pool.
//
// Block = 256 threads (4 waves), 64 vertices/block, lane = vertex.
// Wave wv owns t-octet [wv*8, wv*8+8); per-lane accum = 8t x 8f registers.
// Per r: gather lanes (d2=tid&15 float2, g=tid>>4 vertex) compute interp,
// DFT8 in-register, write spectra Is[v][d][f] (stride 260 -> 2-way max = free).
// GEMM: lane reads its own vertex's spectra (2 b128/d, 2-way = free); W comes
// from s_load (wave-uniform readfirstlane offset) -> zero LDS traffic for W.
// Epilogue: IDFT8 + bias per t, per-wave partial norms, cross-wave LDS
// reduction (all waves compute identical argmax), per-wave t-octet store.
// ---------------------------------------------------------------------------
__global__ __launch_bounds__(256, 2)
void fused_conv_kernel(const float* __restrict__ sig,
                       const int* __restrict__ bc_idx,
                       const float* __restrict__ bc_w,
                       const float* __restrict__ Wsg,
                       const float* __restrict__ bias,
                       float* __restrict__ s_out,
                       int N) {
    __shared__ float Is[64 * 260];   // 66560 B spectral interp, stride 260
    __shared__ float red[64 * 36];   // 9216 B cross-wave norm partials

    int tid = threadIdx.x;
    int vBase = blockIdx.x * 64;
    int lane = tid & 63;
    int wv = tid >> 6;               // t-octet
    int v = vBase + lane;            // lane = vertex
    bool valid = v < N;

    // gather-phase lane roles (float2 granularity)
    int d2 = tid & 15;               // float2 index: floats 2*d2, 2*d2+1
    int g = tid >> 4;                // 0..15

    // accumulators: acc[ti][{C0,C4,R1,I1,R2,I2,R3,I3}]
    float acc[8][8];
    #pragma unroll
    for (int ti = 0; ti < 8; ++ti)
        #pragma unroll
        for (int f = 0; f < 8; ++f) acc[ti][f] = 0.f;

    const v2f rt2 = {RT2, RT2};

    for (int r = 0; r < RR; ++r) {
        __syncthreads();  // previous GEMM done with Is

        // ---- gather + interp + forward DFT8 -> Is ----
        #pragma unroll
        for (int vv0 = 0; vv0 < 4; ++vv0) {
            int vv = g + vv0 * 16;           // 0..63
            int vg = vBase + vv;
            int vgc = (vg < N) ? vg : (N - 1);
            int base = (vgc * 40 + r * 8) * 3;
            v2f xa[8];
            #pragma unroll
            for (int a = 0; a < 8; ++a) {
                int i0 = bc_idx[base + a * 3 + 0];
                int i1 = bc_idx[base + a * 3 + 1];
                int i2 = bc_idx[base + a * 3 + 2];
                float w0 = bc_w[base + a * 3 + 0];
                float w1 = bc_w[base + a * 3 + 1];
                float w2 = bc_w[base + a * 3 + 2];
                v2f r0 = *(const v2f*)&sig[(size_t)i0 * 32 + 2 * d2];
                v2f r1 = *(const v2f*)&sig[(size_t)i1 * 32 + 2 * d2];
                v2f r2 = *(const v2f*)&sig[(size_t)i2 * 32 + 2 * d2];
                v2f w0v = {w0, w0};
                v2f w1v = {w1, w1};
                v2f w2v = {w2, w2};
                xa[a] = pkfma(w2v, r2, pkfma(w1v, r1, w0v * r0));
            }
            // DFT8 (2 d-channels packed)
            v2f s0 = xa[0] + xa[4], dd0 = xa[0] - xa[4];
            v2f s1 = xa[1] + xa[5], dd1 = xa[1] - xa[5];
            v2f s2 = xa[2] + xa[6], dd2 = xa[2] - xa[6];
            v2f s3 = xa[3] + xa[7], dd3 = xa[3] - xa[7];
            v2f s02 = s0 + s2, s13 = s1 + s3;
            v2f F0 = s02 + s13, F4 = s02 - s13;
            v2f R2 = s0 - s2, I2 = s3 - s1;
            v2f u = rt2 * (dd1 - dd3), vv_ = rt2 * (dd1 + dd3);
            v2f R1 = dd0 + u, R3 = dd0 - u;
            v2f I1 = -dd2 - vv_, I3 = dd2 - vv_;
            // transpose to per-d spectra and write (4 x b128, 2-way = free)
            float* ob = &Is[vv * 260 + (2 * d2) * 8];
            v4f lo0 = {F0.x, F4.x, R1.x, I1.x};
            v4f lo1 = {R2.x, I2.x, R3.x, I3.x};
            v4f hi0 = {F0.y, F4.y, R1.y, I1.y};
            v4f hi1 = {R2.y, I2.y, R3.y, I3.y};
            *(v4f*)&ob[0] = lo0;
            *(v4f*)&ob[4] = lo1;
            *(v4f*)&ob[8] = hi0;
            *(v4f*)&ob[12] = hi1;
        }
        __syncthreads();

        // ---- spectral GEMM for this r: W via scalar pipe ----
        const float* ip = &Is[lane * 260];
        int woff = __builtin_amdgcn_readfirstlane((r * 4 + wv) * 2048);
        const float* wr = Wsg + woff;
        #pragma unroll 2
        for (int d = 0; d < 32; ++d) {
            v4f p0 = *(const v4f*)&ip[d * 8];       // [F0,F4,Re1,Im1]
            v4f p1 = *(const v4f*)&ip[d * 8 + 4];   // [Re2,Im2,Re3,Im3]
            const float* wd = wr + d * 64;
            #pragma unroll
            for (int ti = 0; ti < 8; ++ti) {
                float w0 = wd[ti * 8 + 0];
                float w1 = wd[ti * 8 + 1];
                float w2 = wd[ti * 8 + 2];
                float w3 = wd[ti * 8 + 3];
                float w4 = wd[ti * 8 + 4];
                float w5 = wd[ti * 8 + 5];
                float w6 = wd[ti * 8 + 6];
                float w7 = wd[ti * 8 + 7];
                acc[ti][0] = fmaf(p0.x, w0, acc[ti][0]);
                acc[ti][1] = fmaf(p0.y, w1, acc[ti][1]);
                acc[ti][2] = fmaf(p0.z, w2, fmaf(p0.w, w3, acc[ti][2]));
                acc[ti][3] = fmaf(p0.w, w2, fmaf(-p0.z, w3, acc[ti][3]));
                acc[ti][4] = fmaf(p1.x, w4, fmaf(p1.y, w5, acc[ti][4]));
                acc[ti][5] = fmaf(p1.y, w4, fmaf(-p1.x, w5, acc[ti][5]));
                acc[ti][6] = fmaf(p1.z, w6, fmaf(p1.w, w7, acc[ti][6]));
                acc[ti][7] = fmaf(p1.w, w6, fmaf(-p1.z, w7, acc[ti][7]));
            }
        }
    }

    // ---- IDFT8 + bias per t (this wave's t-octet) ----
    float outk[8][8];  // [k][ti]
    #pragma unroll
    for (int ti = 0; ti < 8; ++ti) {
        float C0 = acc[ti][0], C4 = acc[ti][1];
        float R1 = acc[ti][2], I1 = acc[ti][3];
        float R2 = acc[ti][4], I2 = acc[ti][5];
        float R3 = acc[ti][6], I3 = acc[ti][7];
        float e = 0.125f * (C0 + C4), o = 0.125f * (C0 - C4);
        float p = 0.25f * (R1 + R3), q = 0.25f * R2, s = 0.25f * (I1 - I3);
        float a_ = 0.25f * RT2 * (R1 - R3);
        float b_ = 0.25f * RT2 * (I1 + I3);
        float c_ = 0.25f * I2;
        float bb = bias[wv * 8 + ti];
        outk[0][ti] = e + p + q + bb;
        outk[1][ti] = o + a_ - b_ - c_ + bb;
        outk[2][ti] = e - s - q + bb;
        outk[3][ti] = o - a_ - b_ + c_ + bb;
        outk[4][ti] = e - p + q + bb;
        outk[5][ti] = o - a_ + b_ - c_ + bb;
        outk[6][ti] = e + s - q + bb;
        outk[7][ti] = o + a_ + b_ + c_ + bb;
    }

    // ---- per-wave partial norms -> LDS, cross-wave reduce ----
    float pn[8];
    #pragma unroll
    for (int k = 0; k < 8; ++k) {
        float s = 0.f;
        #pragma unroll
        for (int ti = 0; ti < 8; ++ti) s = fmaf(outk[k][ti], outk[k][ti], s);
        pn[k] = s;
    }
    {
        float* rb = &red[lane * 36 + wv * 8];
        *(v4f*)&rb[0] = (v4f){pn[0], pn[1], pn[2], pn[3]};
        *(v4f*)&rb[4] = (v4f){pn[4], pn[5], pn[6], pn[7]};
    }
    __syncthreads();

    float norms[8];
    #pragma unroll
    for (int k = 0; k < 8; ++k) norms[k] = 0.f;
    #pragma unroll
    for (int w = 0; w < 4; ++w) {
        v4f a = *(const v4f*)&red[lane * 36 + w * 8];
        v4f b = *(const v4f*)&red[lane * 36 + w * 8 + 4];
        norms[0] += a.x; norms[1] += a.y; norms[2] += a.z; norms[3] += a.w;
        norms[4] += b.x; norms[5] += b.y; norms[6] += b.z; norms[7] += b.w;
    }
    // argmax_k sqrt(norm), first-max-wins (identical across all 4 waves)
    float best = -1.f;
    int bk = 0;
    #pragma unroll
    for (int k = 0; k < 8; ++k) {
        float n = sqrtf(norms[k]);
        if (n > best) { best = n; bk = k; }
    }

    if (valid) {
        float sel[8];
        #pragma unroll
        for (int ti = 0; ti < 8; ++ti) sel[ti] = 0.f;
        #pragma unroll
        for (int k = 0; k < 8; ++k) {
            if (k == bk) {
                #pragma unroll
                for (int ti = 0; ti < 8; ++ti) sel[ti] = outk[k][ti];
            }
        }
        float* o = s_out + (size_t)v * 32 + wv * 8;
        *(v4f*)&o[0] = (v4f){sel[0], sel[1], sel[2], sel[3]};
        *(v4f*)&o[4] = (v4f){sel[4], sel[5], sel[6], sel[7]};
    }
}

// ---------------------------------------------------------------------------
// Stats: per-column (t) sum and sumsq over N rows, fp64 accumulation.
// ---------------------------------------------------------------------------
__global__ void stats_kernel(const float* __restrict__ s,
                             double* __restrict__ sums,
                             double* __restrict__ sumsq, int n) {
    __shared__ double la[256];
    __shared__ double lb[256];
    int tid = threadIdx.x;
    int t = tid & 31;
    int row = tid >> 5;  // 0..7
    double a = 0.0, b = 0.0;
    for (int v = blockIdx.x * 8 + row; v < n; v += gridDim.x * 8) {
        float x = s[(size_t)v * 32 + t];
        a += (double)x;
        b += (double)x * (double)x;
    }
    la[tid] = a; lb[tid] = b;
    __syncthreads();
    for (int off = 128; off >= 32; off >>= 1) {
        if (tid < off) { la[tid] += la[tid + off]; lb[tid] += lb[tid + off]; }
        __syncthreads();
    }
    if (tid < 32) {
        atomicAdd(&sums[t], la[tid]);
        atomicAdd(&sumsq[t], lb[tid]);
    }
}

// ---------------------------------------------------------------------------
// Finalize BN: scale = gamma * rsqrt(var + eps), shift = beta - mu*scale
// ---------------------------------------------------------------------------
__global__ void finalize_kernel(const double* __restrict__ sums,
                                const double* __restrict__ sumsq,
                                const float* __restrict__ gamma,
                                const float* __restrict__ beta,
                                float* __restrict__ scale,
                                float* __restrict__ shift, int n) {
    int t = threadIdx.x;
    if (t < 32) {
        double mu = sums[t] / (double)n;
        double var = sumsq[t] / (double)n - mu * mu;
        double sc = (double)gamma[t] / sqrt(var + 1e-3);
        scale[t] = (float)sc;
        shift[t] = (float)((double)beta[t] - mu * sc);
    }
}

// ---------------------------------------------------------------------------
// sig2 = relu(scale*s + shift)   (branch 1 epilogue -> conv2 input)
// ---------------------------------------------------------------------------
__global__ void affine_relu_kernel(const float* __restrict__ s,
                                   const float* __restrict__ scale,
                                   const float* __restrict__ shift,
                                   float* __restrict__ o, int n4) {
    int e = blockIdx.x * blockDim.x + threadIdx.x;
    if (e >= n4) return;
    int t0 = (e & 7) * 4;
    float4 x = ((const float4*)s)[e];
    float4 y;
    y.x = fmaxf(fmaf(scale[t0 + 0], x.x, shift[t0 + 0]), 0.f);
    y.y = fmaxf(fmaf(scale[t0 + 1], x.y, shift[t0 + 1]), 0.f);
    y.z = fmaxf(fmaf(scale[t0 + 2], x.z, shift[t0 + 2]), 0.f);
    y.w = fmaxf(fmaf(scale[t0 + 3], x.w, shift[t0 + 3]), 0.f);
    ((float4*)o)[e] = y;
}

// ---------------------------------------------------------------------------
// out = relu(scale*s + shift + signal)   (final residual epilogue)
// ---------------------------------------------------------------------------
__global__ void final_kernel(const float* __restrict__ s,
                             const float* __restrict__ scale,
                             const float* __restrict__ shift,
                             const float* __restrict__ sig,
                             float* __restrict__ o, int n4) {
    int e = blockIdx.x * blockDim.x + threadIdx.x;
    if (e >= n4) return;
    int t0 = (e & 7) * 4;
    float4 x = ((const float4*)s)[e];
    float4 z = ((const float4*)sig)[e];
    float4 y;
    y.x = fmaxf(fmaf(scale[t0 + 0], x.x, shift[t0 + 0]) + z.x, 0.f);
    y.y = fmaxf(fmaf(scale[t0 + 1], x.y, shift[t0 + 1]) + z.y, 0.f);
    y.z = fmaxf(fmaf(scale[t0 + 2], x.z, shift[t0 + 2]) + z.z, 0.f);
    y.w = fmaxf(fmaf(scale[t0 + 3], x.w, shift[t0 + 3]) + z.w, 0.f);
    ((float4*)o)[e] = y;
}

__global__ void zero_stats_kernel(double* __restrict__ d, float* __restrict__ f) {
    int t = threadIdx.x;
    if (t < 128) d[t] = 0.0;
    if (t < 128) f[t] = 0.f;
}

// ---------------------------------------------------------------------------
extern "C" void kernel_launch(void* const* d_in, const int* in_sizes, int n_in,
                              void* d_out, int out_size, void* d_ws, size_t ws_size,
                              hipStream_t stream) {
    const float* signal = (const float*)d_in[0];
    const int* bc_idx   = (const int*)d_in[1];
    const float* bc_w   = (const float*)d_in[2];
    const float* W1     = (const float*)d_in[3];
    const float* b1     = (const float*)d_in[4];
    const float* g1     = (const float*)d_in[5];
    const float* be1    = (const float*)d_in[6];
    const float* W2     = (const float*)d_in[7];
    const float* b2     = (const float*)d_in[8];
    const float* g2     = (const float*)d_in[9];
    const float* be2    = (const float*)d_in[10];
    float* out = (float*)d_out;

    const int N = in_sizes[0] / 32;  // 80000

    char* ws = (char*)d_ws;
    double* sums1  = (double*)ws;         // 32
    double* sumsq1 = sums1 + 32;
    double* sums2  = sums1 + 64;
    double* sumsq2 = sums1 + 96;
    float* scale1 = (float*)(ws + 1024);
    float* shift1 = scale1 + 32;
    float* scale2 = scale1 + 64;
    float* shift2 = scale1 + 96;
    float* Ws1 = (float*)(ws + 4096);                 // 40960 floats = 160 KB
    float* Ws2 = Ws1 + TT * RR * 256;
    float* s1  = Ws2 + TT * RR * 256;
    float* sg2 = s1 + (size_t)N * 32;
    float* s2  = sg2 + (size_t)N * 32;

    int nBlocks = (N + 63) / 64;               // 1250
    int wBlocks = (TT * RR * DD + 255) / 256;  // 20

    zero_stats_kernel<<<1, 128, 0, stream>>>((double*)ws, (float*)(ws + 1024));
    wdft_kernel<<<wBlocks, 256, 0, stream>>>(W1, Ws1);
    wdft_kernel<<<wBlocks, 256, 0, stream>>>(W2, Ws2);

    // ---- branch 1: fused gather+DFT+spectral-conv+pool ----
    fused_conv_kernel<<<nBlocks, 256, 0, stream>>>(signal, bc_idx, bc_w, Ws1, b1, s1, N);
    stats_kernel<<<64, 256, 0, stream>>>(s1, sums1, sumsq1, N);
    finalize_kernel<<<1, 32, 0, stream>>>(sums1, sumsq1, g1, be1, scale1, shift1, N);
    affine_relu_kernel<<<(N * 8 + 255) / 256, 256, 0, stream>>>(s1, scale1, shift1, sg2, N * 8);

    // ---- branch 2 ----
    fused_conv_kernel<<<nBlocks, 256, 0, stream>>>(sg2, bc_idx, bc_w, Ws2, b2, s2, N);
    stats_kernel<<<64, 256, 0, stream>>>(s2, sums2, sumsq2, N);
    finalize_kernel<<<1, 32, 0, stream>>>(sums2, sumsq2, g2, be2, scale2, shift2, N);

    // ---- residual + relu ----
    final_kernel<<<(N * 8 + 255) / 256, 256, 0, stream>>>(s2, scale2, shift2, signal, out, N * 8);
}

// Round 6
// 714.846 us; speedup vs baseline: 2.0042x; 2.0042x over previous
//
#include <hip/hip_runtime.h>
#include <math.h>

// Problem constants (N=80000, Rr=5, A=8, D=32, T=32, K=8 rotations, ROT_DELTA=1)
#define RR 5
#define AA 8
#define DD 32
#define TT 32
#define KK 8

#define RT2 0.70710678118654752f

typedef float v2f __attribute__((ext_vector_type(2)));
typedef float v4f __attribute__((ext_vector_type(4)));

static __device__ __forceinline__ v2f pkfma(v2f a, v2f b, v2f c) {
#if __has_builtin(__builtin_elementwise_fma)
    return __builtin_elementwise_fma(a, b, c);
#else
    v2f r; r.x = fmaf(a.x, b.x, c.x); r.y = fmaf(a.y, b.y, c.y); return r;
#endif
}

// ---------------------------------------------------------------------------
// W spectral precompute -> layout [r][d][t][f], f-pack = [F0,F4,R1,I1,R2,I2,R3,I3]
//   Ws[((r*32 + d)*32 + t)*8 + f]
// so the kernel's LDS staging is a straight contiguous vector copy.
// One thread per (t,r,d) = 5120.
// ---------------------------------------------------------------------------
__global__ void wdft_kernel(const float* __restrict__ W, float* __restrict__ Ws) {
    int idx = blockIdx.x * 256 + threadIdx.x;
    if (idx >= TT * RR * DD) return;
    int d = idx & 31;
    int tr = idx >> 5;      // t*5+r
    int t = tr / 5;
    int r = tr - t * 5;
    float xa[8];
    #pragma unroll
    for (int a = 0; a < 8; ++a) xa[a] = W[(tr * 8 + a) * 32 + d];
    float s0 = xa[0] + xa[4], d0 = xa[0] - xa[4];
    float s1 = xa[1] + xa[5], d1 = xa[1] - xa[5];
    float s2 = xa[2] + xa[6], d2 = xa[2] - xa[6];
    float s3 = xa[3] + xa[7], d3 = xa[3] - xa[7];
    float s02 = s0 + s2, s13 = s1 + s3;
    float F0 = s02 + s13, F4 = s02 - s13;
    float R2 = s0 - s2, I2 = s3 - s1;
    float u = RT2 * (d1 - d3), v = RT2 * (d1 + d3);
    float R1 = d0 + u, R3 = d0 - u;
    float I1 = -d2 - v, I3 = d2 - v;
    float* o = &Ws[(size_t)(((r * 32 + d) * 32 + t) * 8)];
    o[0] = F0; o[1] = F4; o[2] = R1; o[3] = I1;
    o[4] = R2; o[5] = I2; o[6] = R3; o[7] = I3;
}

// ---------------------------------------------------------------------------
// Fused kernel: gather + barycentric interp + forward DFT8 + spectral GEMM
// (vs conj(W-spectrum)) + IDFT8 + bias + angular max pool.
//
// Block = 256 threads (4 waves), 64 vertices/block.
// GEMM lane tile = 2 vertices x 4 t (t = tg+8j): per d, 4 b128 (2 vertex
// spectra) + 8 b128 (4 t W frags) feed 112 MAC -> 9.3 MAC/b128 (vs 5.6 in
// the 1vx4t layout): the LDS issue pipe is the measured bottleneck.
// W is staged per r in 8-d quarter slices (Wl 8.3 KB) so Is(66.6 KB)+Wl
// stays under 80 KB -> 2 blocks/CU.
// Wave wv owns vertices [wv*16, wv*16+16) exclusively -> norm reduction is
// wave-local (shfl over tg only), no cross-wave LDS reduce.
// ---------------------------------------------------------------------------
__global__ __launch_bounds__(256, 2)
void fused_conv_kernel(const float* __restrict__ sig,
                       const int* __restrict__ bc_idx,
                       const float* __restrict__ bc_w,
                       const float* __restrict__ Wsg,
                       const float* __restrict__ bias,
                       float* __restrict__ s_out,
                       int N) {
    __shared__ float Is[64 * 260];   // 66560 B spectral interp, stride 260
    __shared__ float Wl[8 * 260];    // 8320 B quarter W slice [d][t*8+f]

    int tid = threadIdx.x;
    int vBase = blockIdx.x * 64;
    int lane = tid & 63;
    int wv = tid >> 6;

    // GEMM lane roles: vg = vertex-pair, tg = t-group
    int vg = lane & 7;
    int tg = lane >> 3;              // 0..7
    int v0L = wv * 16 + vg * 2;      // local vertex pair base
    int v0 = vBase + v0L;
    int v1 = v0 + 1;

    // gather-phase lane roles (float2 granularity)
    int d2 = tid & 15;               // float2 index: floats 2*d2, 2*d2+1
    int g = tid >> 4;                // 0..15

    // spectral accumulators per (vv in {0,1}, j in 0..3):
    // A0=(C0,C4) A1=(R1,I1) A2=(R2,I2) A3=(R3,I3)
    v2f A0[2][4], A1[2][4], A2[2][4], A3[2][4];
    #pragma unroll
    for (int vv = 0; vv < 2; ++vv)
        #pragma unroll
        for (int j = 0; j < 4; ++j) {
            A0[vv][j] = (v2f){0.f, 0.f}; A1[vv][j] = (v2f){0.f, 0.f};
            A2[vv][j] = (v2f){0.f, 0.f}; A3[vv][j] = (v2f){0.f, 0.f};
        }

    const v2f rt2 = {RT2, RT2};
    const v4f* Ws4 = (const v4f*)Wsg;

    for (int r = 0; r < RR; ++r) {
        __syncthreads();  // previous r's GEMM done with Is

        // ---- gather + interp + forward DFT8 -> Is ----
        #pragma unroll
        for (int vv0 = 0; vv0 < 4; ++vv0) {
            int vv = g + vv0 * 16;           // 0..63
            int vgl = vBase + vv;
            int vgc = (vgl < N) ? vgl : (N - 1);
            int base = (vgc * 40 + r * 8) * 3;
            v2f xa[8];
            #pragma unroll
            for (int a = 0; a < 8; ++a) {
                int i0 = bc_idx[base + a * 3 + 0];
                int i1 = bc_idx[base + a * 3 + 1];
                int i2 = bc_idx[base + a * 3 + 2];
                float w0 = bc_w[base + a * 3 + 0];
                float w1 = bc_w[base + a * 3 + 1];
                float w2 = bc_w[base + a * 3 + 2];
                v2f r0 = *(const v2f*)&sig[(size_t)i0 * 32 + 2 * d2];
                v2f r1 = *(const v2f*)&sig[(size_t)i1 * 32 + 2 * d2];
                v2f r2 = *(const v2f*)&sig[(size_t)i2 * 32 + 2 * d2];
                v2f w0v = {w0, w0};
                v2f w1v = {w1, w1};
                v2f w2v = {w2, w2};
                xa[a] = pkfma(w2v, r2, pkfma(w1v, r1, w0v * r0));
            }
            // DFT8 (2 d-channels packed)
            v2f s0 = xa[0] + xa[4], dd0 = xa[0] - xa[4];
            v2f s1 = xa[1] + xa[5], dd1 = xa[1] - xa[5];
            v2f s2 = xa[2] + xa[6], dd2 = xa[2] - xa[6];
            v2f s3 = xa[3] + xa[7], dd3 = xa[3] - xa[7];
            v2f s02 = s0 + s2, s13 = s1 + s3;
            v2f F0 = s02 + s13, F4 = s02 - s13;
            v2f R2 = s0 - s2, I2 = s3 - s1;
            v2f u = rt2 * (dd1 - dd3), vvv = rt2 * (dd1 + dd3);
            v2f R1 = dd0 + u, R3 = dd0 - u;
            v2f I1 = -dd2 - vvv, I3 = dd2 - vvv;
            // transpose to per-d spectra and write (4 x b128)
            float* ob = &Is[vv * 260 + (2 * d2) * 8];
            *(v4f*)&ob[0]  = (v4f){F0.x, F4.x, R1.x, I1.x};
            *(v4f*)&ob[4]  = (v4f){R2.x, I2.x, R3.x, I3.x};
            *(v4f*)&ob[8]  = (v4f){F0.y, F4.y, R1.y, I1.y};
            *(v4f*)&ob[12] = (v4f){R2.y, I2.y, R3.y, I3.y};
        }

        // ---- 4 W quarter-stages of 8 d each ----
        for (int ws = 0; ws < 4; ++ws) {
            __syncthreads();  // ws=0: gather visible; ws>0: prev GEMM done with Wl
            {
                // stage Ws[r][ws*8 .. ws*8+8)[t][f] -> Wl (2048 floats)
                const v4f* src = Ws4 + (size_t)(r * 32 + ws * 8) * 64;
                int dl = tid >> 5;                 // 0..7
                int rem = (tid * 8) & 255;
                float* dst = &Wl[dl * 260 + rem];
                v4f a = src[tid * 2];
                v4f b = src[tid * 2 + 1];
                *(v4f*)dst = a;
                *(v4f*)(dst + 4) = b;
            }
            __syncthreads();  // Wl visible

            #pragma unroll 2
            for (int dl = 0; dl < 8; ++dl) {
                int dg = ws * 8 + dl;
                const float* ip = &Is[v0L * 260 + dg * 8];
                v4f pa0 = *(const v4f*)&ip[0];
                v4f pb0 = *(const v4f*)&ip[4];
                v4f pa1 = *(const v4f*)&ip[260];
                v4f pb1 = *(const v4f*)&ip[264];
                v2f x1_0 = pa0.zw, x1n_0 = {pa0.w, -pa0.z};
                v2f x2_0 = pb0.xy, x2n_0 = {pb0.y, -pb0.x};
                v2f x3_0 = pb0.zw, x3n_0 = {pb0.w, -pb0.z};
                v2f x1_1 = pa1.zw, x1n_1 = {pa1.w, -pa1.z};
                v2f x2_1 = pb1.xy, x2n_1 = {pb1.y, -pb1.x};
                v2f x3_1 = pb1.zw, x3n_1 = {pb1.w, -pb1.z};
                const float* wrow = &Wl[dl * 260];
                #pragma unroll
                for (int j = 0; j < 4; ++j) {
                    v4f q0 = *(const v4f*)&wrow[(tg + 8 * j) * 8];
                    v4f q1 = *(const v4f*)&wrow[(tg + 8 * j) * 8 + 4];
                    v2f w2v = {q0.z, q0.z}, w3v = {q0.w, q0.w};
                    v2f w4v = {q1.x, q1.x}, w5v = {q1.y, q1.y};
                    v2f w6v = {q1.z, q1.z}, w7v = {q1.w, q1.w};
                    // vv = 0
                    A0[0][j] = pkfma(pa0.xy, q0.xy, A0[0][j]);
                    A1[0][j] = pkfma(x1_0, w2v, A1[0][j]);
                    A1[0][j] = pkfma(x1n_0, w3v, A1[0][j]);
                    A2[0][j] = pkfma(x2_0, w4v, A2[0][j]);
                    A2[0][j] = pkfma(x2n_0, w5v, A2[0][j]);
                    A3[0][j] = pkfma(x3_0, w6v, A3[0][j]);
                    A3[0][j] = pkfma(x3n_0, w7v, A3[0][j]);
                    // vv = 1
                    A0[1][j] = pkfma(pa1.xy, q0.xy, A0[1][j]);
                    A1[1][j] = pkfma(x1_1, w2v, A1[1][j]);
                    A1[1][j] = pkfma(x1n_1, w3v, A1[1][j]);
                    A2[1][j] = pkfma(x2_1, w4v, A2[1][j]);
                    A2[1][j] = pkfma(x2n_1, w5v, A2[1][j]);
                    A3[1][j] = pkfma(x3_1, w6v, A3[1][j]);
                    A3[1][j] = pkfma(x3n_1, w7v, A3[1][j]);
                }
            }
        }
    }

    // ---- IDFT8 + bias per (vv, t) ----
    float bj[4];
    #pragma unroll
    for (int j = 0; j < 4; ++j) bj[j] = bias[tg + 8 * j];

    float outk[2][8][4];  // [vv][k][j]
    #pragma unroll
    for (int vv = 0; vv < 2; ++vv) {
        #pragma unroll
        for (int j = 0; j < 4; ++j) {
            float C0 = A0[vv][j].x, C4 = A0[vv][j].y;
            float R1 = A1[vv][j].x, I1 = A1[vv][j].y;
            float R2 = A2[vv][j].x, I2 = A2[vv][j].y;
            float R3 = A3[vv][j].x, I3 = A3[vv][j].y;
            float e = 0.125f * (C0 + C4), o = 0.125f * (C0 - C4);
            float p = 0.25f * (R1 + R3), q = 0.25f * R2, s = 0.25f * (I1 - I3);
            float a_ = 0.25f * RT2 * (R1 - R3);
            float b_ = 0.25f * RT2 * (I1 + I3);
            float c_ = 0.25f * I2;
            float bb = bj[j];
            outk[vv][0][j] = e + p + q + bb;
            outk[vv][1][j] = o + a_ - b_ - c_ + bb;
            outk[vv][2][j] = e - s - q + bb;
            outk[vv][3][j] = o - a_ - b_ + c_ + bb;
            outk[vv][4][j] = e - p + q + bb;
            outk[vv][5][j] = o - a_ + b_ - c_ + bb;
            outk[vv][6][j] = e + s - q + bb;
            outk[vv][7][j] = o + a_ + b_ + c_ + bb;
        }
    }

    // ---- norms: wave-local reduce over tg (lane bits 3..5) ----
    #pragma unroll
    for (int vv = 0; vv < 2; ++vv) {
        float norms[8];
        #pragma unroll
        for (int k = 0; k < 8; ++k) {
            float nl = 0.f;
            #pragma unroll
            for (int j = 0; j < 4; ++j)
                nl = fmaf(outk[vv][k][j], outk[vv][k][j], nl);
            nl += __shfl_xor(nl, 8);
            nl += __shfl_xor(nl, 16);
            nl += __shfl_xor(nl, 32);
            norms[k] = nl;
        }
        float best = -1.f;
        int bk = 0;
        #pragma unroll
        for (int k = 0; k < 8; ++k) {
            float n = sqrtf(norms[k]);
            if (n > best) { best = n; bk = k; }
        }
        int vOut = (vv == 0) ? v0 : v1;
        if (vOut < N) {
            float sel[4];
            #pragma unroll
            for (int j = 0; j < 4; ++j) sel[j] = 0.f;
            #pragma unroll
            for (int k = 0; k < 8; ++k) {
                if (k == bk) {
                    #pragma unroll
                    for (int j = 0; j < 4; ++j) sel[j] = outk[vv][k][j];
                }
            }
            float* o = s_out + (size_t)vOut * 32 + tg;
            o[0]  = sel[0];
            o[8]  = sel[1];
            o[16] = sel[2];
            o[24] = sel[3];
        }
    }
}

// ---------------------------------------------------------------------------
// Stats: per-column (t) sum and sumsq over N rows, fp64 accumulation.
// ---------------------------------------------------------------------------
__global__ void stats_kernel(const float* __restrict__ s,
                             double* __restrict__ sums,
                             double* __restrict__ sumsq, int n) {
    __shared__ double la[256];
    __shared__ double lb[256];
    int tid = threadIdx.x;
    int t = tid & 31;
    int row = tid >> 5;  // 0..7
    double a = 0.0, b = 0.0;
    for (int v = blockIdx.x * 8 + row; v < n; v += gridDim.x * 8) {
        float x = s[(size_t)v * 32 + t];
        a += (double)x;
        b += (double)x * (double)x;
    }
    la[tid] = a; lb[tid] = b;
    __syncthreads();
    for (int off = 128; off >= 32; off >>= 1) {
        if (tid < off) { la[tid] += la[tid + off]; lb[tid] += lb[tid + off]; }
        __syncthreads();
    }
    if (tid < 32) {
        atomicAdd(&sums[t], la[tid]);
        atomicAdd(&sumsq[t], lb[tid]);
    }
}

// ---------------------------------------------------------------------------
// Finalize BN: scale = gamma * rsqrt(var + eps), shift = beta - mu*scale
// ---------------------------------------------------------------------------
__global__ void finalize_kernel(const double* __restrict__ sums,
                                const double* __restrict__ sumsq,
                                const float* __restrict__ gamma,
                                const float* __restrict__ beta,
                                float* __restrict__ scale,
                                float* __restrict__ shift, int n) {
    int t = threadIdx.x;
    if (t < 32) {
        double mu = sums[t] / (double)n;
        double var = sumsq[t] / (double)n - mu * mu;
        double sc = (double)gamma[t] / sqrt(var + 1e-3);
        scale[t] = (float)sc;
        shift[t] = (float)((double)beta[t] - mu * sc);
    }
}

// ---------------------------------------------------------------------------
// sig2 = relu(scale*s + shift)   (branch 1 epilogue -> conv2 input)
// ---------------------------------------------------------------------------
__global__ void affine_relu_kernel(const float* __restrict__ s,
                                   const float* __restrict__ scale,
                                   const float* __restrict__ shift,
                                   float* __restrict__ o, int n4) {
    int e = blockIdx.x * blockDim.x + threadIdx.x;
    if (e >= n4) return;
    int t0 = (e & 7) * 4;
    float4 x = ((const float4*)s)[e];
    float4 y;
    y.x = fmaxf(fmaf(scale[t0 + 0], x.x, shift[t0 + 0]), 0.f);
    y.y = fmaxf(fmaf(scale[t0 + 1], x.y, shift[t0 + 1]), 0.f);
    y.z = fmaxf(fmaf(scale[t0 + 2], x.z, shift[t0 + 2]), 0.f);
    y.w = fmaxf(fmaf(scale[t0 + 3], x.w, shift[t0 + 3]), 0.f);
    ((float4*)o)[e] = y;
}

// ---------------------------------------------------------------------------
// out = relu(scale*s + shift + signal)   (final residual epilogue)
// ---------------------------------------------------------------------------
__global__ void final_kernel(const float* __restrict__ s,
                             const float* __restrict__ scale,
                             const float* __restrict__ shift,
                             const float* __restrict__ sig,
                             float* __restrict__ o, int n4) {
    int e = blockIdx.x * blockDim.x + threadIdx.x;
    if (e >= n4) return;
    int t0 = (e & 7) * 4;
    float4 x = ((const float4*)s)[e];
    float4 z = ((const float4*)sig)[e];
    float4 y;
    y.x = fmaxf(fmaf(scale[t0 + 0], x.x, shift[t0 + 0]) + z.x, 0.f);
    y.y = fmaxf(fmaf(scale[t0 + 1], x.y, shift[t0 + 1]) + z.y, 0.f);
    y.z = fmaxf(fmaf(scale[t0 + 2], x.z, shift[t0 + 2]) + z.z, 0.f);
    y.w = fmaxf(fmaf(scale[t0 + 3], x.w, shift[t0 + 3]) + z.w, 0.f);
    ((float4*)o)[e] = y;
}

__global__ void zero_stats_kernel(double* __restrict__ d, float* __restrict__ f) {
    int t = threadIdx.x;
    if (t < 128) d[t] = 0.0;
    if (t < 128) f[t] = 0.f;
}

// ---------------------------------------------------------------------------
extern "C" void kernel_launch(void* const* d_in, const int* in_sizes, int n_in,
                              void* d_out, int out_size, void* d_ws, size_t ws_size,
                              hipStream_t stream) {
    const float* signal = (const float*)d_in[0];
    const int* bc_idx   = (const int*)d_in[1];
    const float* bc_w   = (const float*)d_in[2];
    const float* W1     = (const float*)d_in[3];
    const float* b1     = (const float*)d_in[4];
    const float* g1     = (const float*)d_in[5];
    const float* be1    = (const float*)d_in[6];
    const float* W2     = (const float*)d_in[7];
    const float* b2     = (const float*)d_in[8];
    const float* g2     = (const float*)d_in[9];
    const float* be2    = (const float*)d_in[10];
    float* out = (float*)d_out;

    const int N = in_sizes[0] / 32;  // 80000

    char* ws = (char*)d_ws;
    double* sums1  = (double*)ws;         // 32
    double* sumsq1 = sums1 + 32;
    double* sums2  = sums1 + 64;
    double* sumsq2 = sums1 + 96;
    float* scale1 = (float*)(ws + 1024);
    float* shift1 = scale1 + 32;
    float* scale2 = scale1 + 64;
    float* shift2 = scale1 + 96;
    float* Ws1 = (float*)(ws + 4096);                 // 40960 floats = 160 KB
    float* Ws2 = Ws1 + RR * DD * TT * 8;
    float* s1  = Ws2 + RR * DD * TT * 8;
    float* sg2 = s1 + (size_t)N * 32;
    float* s2  = sg2 + (size_t)N * 32;

    int nBlocks = (N + 63) / 64;               // 1250
    int wBlocks = (TT * RR * DD + 255) / 256;  // 20

    zero_stats_kernel<<<1, 128, 0, stream>>>((double*)ws, (float*)(ws + 1024));
    wdft_kernel<<<wBlocks, 256, 0, stream>>>(W1, Ws1);
    wdft_kernel<<<wBlocks, 256, 0, stream>>>(W2, Ws2);

    // ---- branch 1: fused gather+DFT+spectral-conv+pool ----
    fused_conv_kernel<<<nBlocks, 256, 0, stream>>>(signal, bc_idx, bc_w, Ws1, b1, s1, N);
    stats_kernel<<<64, 256, 0, stream>>>(s1, sums1, sumsq1, N);
    finalize_kernel<<<1, 32, 0, stream>>>(sums1, sumsq1, g1, be1, scale1, shift1, N);
    affine_relu_kernel<<<(N * 8 + 255) / 256, 256, 0, stream>>>(s1, scale1, shift1, sg2, N * 8);

    // ---- branch 2 ----
    fused_conv_kernel<<<nBlocks, 256, 0, stream>>>(sg2, bc_idx, bc_w, Ws2, b2, s2, N);
    stats_kernel<<<64, 256, 0, stream>>>(s2, sums2, sumsq2, N);
    finalize_kernel<<<1, 32, 0, stream>>>(sums2, sumsq2, g2, be2, scale2, shift2, N);

    // ---- residual + relu ----
    final_kernel<<<(N * 8 + 255) / 256, 256, 0, stream>>>(s2, scale2, shift2, signal, out, N * 8);
}